// Round 11
// baseline (877.449 us; speedup 1.0000x reference)
//
#include <hip/hip_runtime.h>
#include <hip/hip_fp16.h>

#define HID   128
#define WARM  80
#define NCHUNK 256

// ---------------- graph prep ----------------

__global__ void detect_k(const int* __restrict__ e, int* __restrict__ mode) {
  if (threadIdx.x == 0 && blockIdx.x == 0) {
    int z = 0;
#pragma unroll
    for (int k = 0; k < 8; ++k) z |= e[2 * k + 1];
    *mode = (z == 0) ? 1 : 0;  // 1 = int64, 0 = int32
  }
}

__global__ void deg_k(const int* __restrict__ e, const int* __restrict__ mode,
                      int* __restrict__ cnt, int E) {
  const int m = *mode;
  for (int i = blockIdx.x * 256 + threadIdx.x; i < E; i += gridDim.x * 256) {
    int d = m ? e[2 * (E + i)] : e[E + i];
    atomicAdd(&cnt[d], 1);
  }
}

__global__ void fill_k(const int* __restrict__ e, const int* __restrict__ mode,
                       int* __restrict__ cursor, int* __restrict__ csr, int E) {
  const int m = *mode;
  for (int i = blockIdx.x * 256 + threadIdx.x; i < E; i += gridDim.x * 256) {
    int s = m ? e[2 * i] : e[i];
    int d = m ? e[2 * (E + i)] : e[E + i];
    int p = atomicAdd(&cursor[d], 1);
    csr[p] = s;
  }
}

// ---------------- parallel scan (3 kernels, integer-exact) ----------------
__global__ __launch_bounds__(1024) void scan1_k(const int* __restrict__ cnt,
                                                int* __restrict__ off,
                                                int* __restrict__ tot, int n) {
  __shared__ int wsum[16];
  const int tid = threadIdx.x, lane = tid & 63, wv = tid >> 6;
  const int i = blockIdx.x * 1024 + tid;
  int v = (i < n) ? cnt[i] : 0;
  int x = v;
#pragma unroll
  for (int s = 1; s < 64; s <<= 1) {
    int y = __shfl_up(x, (unsigned)s, 64);
    if (lane >= s) x += y;
  }
  if (lane == 63) wsum[wv] = x;
  __syncthreads();
  int wpre = 0, t = 0;
#pragma unroll
  for (int q = 0; q < 16; ++q) {
    int s = wsum[q];
    t += s;
    if (q < wv) wpre += s;
  }
  if (i < n) off[i] = wpre + x - v;
  if (tid == 0) tot[blockIdx.x] = t;
}

__global__ void scan2_k(int* __restrict__ tot, int nb) {
  const int lane = threadIdx.x & 63;
  int v = (lane < nb) ? tot[lane] : 0;
  int x = v;
#pragma unroll
  for (int s = 1; s < 64; s <<= 1) {
    int y = __shfl_up(x, (unsigned)s, 64);
    if (lane >= s) x += y;
  }
  if (lane < nb) tot[lane] = x - v;
}

__global__ void scan3_k(int* __restrict__ off, const int* __restrict__ tot,
                        int* __restrict__ cursor, const int* __restrict__ cnt,
                        float* __restrict__ dinv, int n) {
  const int i = blockIdx.x * 256 + threadIdx.x;
  if (i < n) {
    int o = off[i] + tot[i >> 10];
    off[i] = o;
    cursor[i] = o;
    dinv[i] = rsqrtf((float)(cnt[i] + 1));
  }
}

// ---------------- f32 -> f16 conversion helpers ----------------
struct half4s { __half2 a, b; };

__global__ void cast_k(const float* __restrict__ src, __half* __restrict__ dst,
                       int n4) {
  for (int i = blockIdx.x * 256 + threadIdx.x; i < n4; i += gridDim.x * 256) {
    float4 v = ((const float4*)src)[i];
    half4s h;
    h.a = __floats2half2_rn(v.x, v.y);
    h.b = __floats2half2_rn(v.z, v.w);
    ((half4s*)dst)[i] = h;
  }
}

// transpose+cast a 128x128 f32 matrix -> f16 [col][row]
__global__ void tcast_k(const float* __restrict__ src, __half* __restrict__ dst) {
  const int idx = blockIdx.x * 256 + threadIdx.x;  // 16384 threads
  const int r = idx >> 7, c = idx & 127;
  dst[(c << 7) + r] = __float2half(src[idx]);
}

// ---------------- MFMA GEMM: C[M x N] = A[M x 128] @ B, K=128 ----------------
// validated round 10: layout per guide §3, no LDS (operands L2/L3-resident)
typedef _Float16 f16x8 __attribute__((ext_vector_type(8)));
typedef float f32x4 __attribute__((ext_vector_type(4)));

template <int EPI>
__global__ __launch_bounds__(256) void mgemm_k(
    const __half* __restrict__ A, const __half* __restrict__ Bt,
    float* __restrict__ Of, __half* __restrict__ Oh, int ostride,
    const float* __restrict__ dinv, const float* __restrict__ bias0,
    const float* __restrict__ bias1, int M) {
  const int tid = threadIdx.x;
  const int wv = tid >> 6, lane = tid & 63;
  const int m0 = blockIdx.x * 64 + wv * 16;
  const int n0 = blockIdx.y * 64;
  const int lrow = lane & 15, lk = lane >> 4;

  int am = m0 + lrow;
  if (am >= M) am = M - 1;
  const __half* ap = A + (long)am * 128 + lk * 8;
  const __half* bp = Bt + (long)(n0 + lrow) * 128 + lk * 8;

  f16x8 afr[4];
#pragma unroll
  for (int s = 0; s < 4; ++s) afr[s] = *(const f16x8*)(ap + s * 32);

  f32x4 acc[4];
#pragma unroll
  for (int nb = 0; nb < 4; ++nb) {
    f32x4 c = {0.f, 0.f, 0.f, 0.f};
#pragma unroll
    for (int s = 0; s < 4; ++s) {
      f16x8 bfr = *(const f16x8*)(bp + (long)nb * 16 * 128 + s * 32);
      c = __builtin_amdgcn_mfma_f32_16x16x32_f16(afr[s], bfr, c, 0, 0, 0);
    }
    acc[nb] = c;
  }

  const int crow0 = m0 + lk * 4;
  const int ccol = n0 + lrow;
#pragma unroll
  for (int j = 0; j < 4; ++j) {
    const int row = crow0 + j;
    if (row >= M) continue;
    if (EPI == 0) {
      const float d = dinv[row];
#pragma unroll
      for (int nb = 0; nb < 4; ++nb)
        Oh[(long)row * ostride + ccol + nb * 16] = __float2half(acc[nb][j] * d);
    } else if (EPI == 1) {
#pragma unroll
      for (int nb = 0; nb < 4; ++nb) {
        const int n = ccol + nb * 16;
        Oh[(long)row * ostride + n] =
            __float2half(acc[nb][j] + bias0[n] + bias1[n]);
      }
    } else {
#pragma unroll
      for (int nb = 0; nb < 4; ++nb) {
        const int n = ccol + nb * 16;
        Of[(long)row * ostride + n] = acc[nb][j] + bias0[n];
      }
    }
  }
}

// ---------------- aggregation: 4 nodes per wave, 16B loads ----------------
// OUT[i] = f16(relu(dinv[i]*(sum HS[src] + HS[i]) + bias)), f32 accum.
// 16 lanes x half8 (16B) per 256B row; per-channel order identical to before.
__global__ __launch_bounds__(256) void agg_k(
    const __half* __restrict__ HS, const int* __restrict__ off,
    const int* __restrict__ cnt, const int* __restrict__ csr,
    const float* __restrict__ dinv, const float* __restrict__ bias,
    __half* __restrict__ OUT, int Nn) {
  const int w = (blockIdx.x * 256 + threadIdx.x) >> 6;
  const int lane = threadIdx.x & 63;
  const int node = w * 4 + (lane >> 4);
  if (node >= Nn) return;
  const int f = (lane & 15) * 8;  // 8 halfs per lane
  const int o0 = off[node];
  const int ce = cnt[node];
  float acc[8];
  {
    uint4 u = *(const uint4*)&HS[(long)node * 128 + f];
    const __half2* hp = (const __half2*)&u;
#pragma unroll
    for (int q = 0; q < 4; ++q) {
      float2 t = __half22float2(hp[q]);
      acc[2 * q] = t.x;
      acc[2 * q + 1] = t.y;
    }
  }
  auto addrow = [&](uint4 u) {
    const __half2* hp = (const __half2*)&u;
#pragma unroll
    for (int q = 0; q < 4; ++q) {
      float2 t = __half22float2(hp[q]);
      acc[2 * q] += t.x;
      acc[2 * q + 1] += t.y;
    }
  };
  int e = 0;
  for (; e + 4 <= ce; e += 4) {
    int s0 = csr[o0 + e + 0];
    int s1 = csr[o0 + e + 1];
    int s2 = csr[o0 + e + 2];
    int s3 = csr[o0 + e + 3];
    uint4 u0 = *(const uint4*)&HS[(long)s0 * 128 + f];
    uint4 u1 = *(const uint4*)&HS[(long)s1 * 128 + f];
    uint4 u2 = *(const uint4*)&HS[(long)s2 * 128 + f];
    uint4 u3 = *(const uint4*)&HS[(long)s3 * 128 + f];
    addrow(u0);
    addrow(u1);
    addrow(u2);
    addrow(u3);
  }
  for (; e < ce; ++e) {
    uint4 u = *(const uint4*)&HS[(long)csr[o0 + e] * 128 + f];
    addrow(u);
  }
  float d = dinv[node];
  __half2 o[4];
#pragma unroll
  for (int q = 0; q < 4; ++q) {
    float bx = bias[f + 2 * q], by = bias[f + 2 * q + 1];
    o[q] = __floats2half2_rn(fmaxf(acc[2 * q] * d + bx, 0.f),
                             fmaxf(acc[2 * q + 1] * d + by, 0.f));
  }
  *(uint4*)&OUT[(long)node * 128 + f] = *(uint4*)o;
}

// ---------------- chunked LSTM: zero-cvt inner loop, bit-exact ----------------
// Numerics identical to the validated round-5/8/9/10 path: weights kept as
// float(f16(w)) in 128 VGPRs, h kept as float(f16(h)) in LDS — the exact
// values the old cvt+fma fallback produced per-iteration, with the same
// 4-accumulator order. Inner loop is now 128 fmaf + 32 ds_read_b128, no cvt.
// Inline-asm v_dot2_f32_f16 FAILED twice (rounds 6,7, ~3.9e-3) — keep out.
// 128 VGPR for weights -> 1 block/CU (launch_bounds(512,1)); NCHUNK=256 gives
// exactly 1 block per CU and cuts warm-up steps (T ∝ N + WARM*NCHUNK).
__global__ __launch_bounds__(512, 1) void lstm_k(
    const __half* __restrict__ XP, const float* __restrict__ Whh,
    __half* __restrict__ HL, int N, int L) {
  __shared__ float hbuf[2][128];
  const int tid = threadIdx.x;
  const int w = tid >> 6, lane = tid & 63;
  const int gate = lane >> 4, sub = lane & 15;
  const int jj = w * 16 + sub;    // 0..127 hidden channel
  const int r = gate * 128 + jj;  // row in [512] gate matrix
  const int ch = blockIdx.x;
  long start = (long)ch * L;
  if (start >= N) return;  // uniform per block
  long t1 = start + L;
  if (t1 > N) t1 = N;
  long t0 = start - WARM;
  if (t0 < 0) t0 = 0;

  // W_hh row r as float(f16(w)): 128 VGPRs, bit-identical to old cvt output
  float wf[128];
  {
    const float2* wp = (const float2*)(Whh + (long)r * 128);
#pragma unroll
    for (int i = 0; i < 64; ++i) {
      float2 fv = wp[i];
      wf[2 * i] = (float)(_Float16)fv.x;
      wf[2 * i + 1] = (float)(_Float16)fv.y;
    }
  }

  if (tid < 128) {
    hbuf[0][tid] = 0.f;
    hbuf[1][tid] = 0.f;
  }
  float cst = 0.f;
  const float m = (gate == 2) ? 2.f : 1.f;  // tanh(x) = 2*sigmoid(2x)-1
  const float mb = 1.f - m;
  __syncthreads();

  int p = 0;
  float xpv = __half2float(XP[t0 * 512 + r]);
  for (long t = t0; t < t1; ++t) {
    float xpn = (t + 1 < t1) ? __half2float(XP[(t + 1) * 512 + r]) : 0.f;
    float a0 = 0.f, a1 = 0.f, a2 = 0.f, a3 = 0.f;
    const float4* hb = (const float4*)&hbuf[p][0];
#pragma unroll
    for (int i = 0; i < 16; ++i) {
      float4 u0 = hb[2 * i];      // h[8i..8i+3]
      float4 u1 = hb[2 * i + 1];  // h[8i+4..8i+7]
      a0 = fmaf(wf[8 * i + 0], u0.x, a0);
      a0 = fmaf(wf[8 * i + 1], u0.y, a0);
      a1 = fmaf(wf[8 * i + 2], u0.z, a1);
      a1 = fmaf(wf[8 * i + 3], u0.w, a1);
      a2 = fmaf(wf[8 * i + 4], u1.x, a2);
      a2 = fmaf(wf[8 * i + 5], u1.y, a2);
      a3 = fmaf(wf[8 * i + 6], u1.z, a3);
      a3 = fmaf(wf[8 * i + 7], u1.w, a3);
    }
    float acc = xpv + ((a0 + a1) + (a2 + a3));
    float y = 1.f / (1.f + __expf(-m * acc));
    float act = fmaf(m, y, mb);  // sigmoid for i,f,o; tanh for g
    float gi = __shfl(act, sub + 0, 64);
    float gf = __shfl(act, sub + 16, 64);
    float gg = __shfl(act, sub + 32, 64);
    float go = __shfl(act, sub + 48, 64);
    cst = fmaf(gf, cst, gi * gg);
    float e = __expf(2.f * cst);
    float th = 1.f - 2.f / (e + 1.f);
    float h = go * th;
    if (gate == 0) {
      __half hh = __float2half(h);
      hbuf[p ^ 1][jj] = __half2float(hh);  // float(f16(h)): bit-exact path
      if (t >= start) HL[t * 128 + jj] = hh;
    }
    __syncthreads();
    p ^= 1;
    xpv = xpn;
  }
}

// ---------------- launch ----------------
extern "C" void kernel_launch(void* const* d_in, const int* in_sizes, int n_in,
                              void* d_out, int out_size, void* d_ws,
                              size_t ws_size, hipStream_t stream) {
  const float* x = (const float*)d_in[0];
  const int* eidx = (const int*)d_in[1];
  const float* W1 = (const float*)d_in[3];
  const float* b1 = (const float*)d_in[4];
  const float* W2 = (const float*)d_in[5];
  const float* b2 = (const float*)d_in[6];
  const float* Wih = (const float*)d_in[7];
  const float* Whh = (const float*)d_in[8];
  const float* bih = (const float*)d_in[9];
  const float* bhh = (const float*)d_in[10];
  const float* Wlin = (const float*)d_in[11];
  const float* blin = (const float*)d_in[12];
  float* out = (float*)d_out;

  const int N = in_sizes[0] / 128;
  const int E = in_sizes[1] / 2;

  size_t cur = 0;
  auto alloc = [&](size_t nbytes) -> char* {
    char* p = (char*)d_ws + cur;
    cur += (nbytes + 255) & ~(size_t)255;
    return p;
  };
  int* mode = (int*)alloc(4);
  int* cnt = (int*)alloc((size_t)N * 4);
  int* off = (int*)alloc((size_t)N * 4);
  int* cursor = (int*)alloc((size_t)N * 4);
  float* dinv = (float*)alloc((size_t)N * 4);
  int* tot = (int*)alloc(64 * 4);
  int* csr = (int*)alloc((size_t)E * 4);
  __half* xh = (__half*)alloc((size_t)N * 128 * 2);
  __half* W1t = (__half*)alloc(16384 * 2);
  __half* W2t = (__half*)alloc(16384 * 2);
  __half* Wih_h = (__half*)alloc(65536 * 2);
  __half* Wlin_h = (__half*)alloc(8192 * 2);
  __half* Ph = (__half*)alloc((size_t)N * 128 * 2);
  __half* Qh = (__half*)alloc((size_t)N * 128 * 2);
  __half* XP = (__half*)alloc((size_t)N * 512 * 2);
  __half* HLh = (__half*)alloc((size_t)N * 128 * 2);

  hipMemsetAsync(cnt, 0, (size_t)N * 4, stream);
  detect_k<<<1, 64, 0, stream>>>(eidx, mode);
  deg_k<<<1024, 256, 0, stream>>>(eidx, mode, cnt, E);
  const int nb = (N + 1023) / 1024;
  scan1_k<<<nb, 1024, 0, stream>>>(cnt, off, tot, N);
  scan2_k<<<1, 64, 0, stream>>>(tot, nb);
  scan3_k<<<(N + 255) / 256, 256, 0, stream>>>(off, tot, cursor, cnt, dinv, N);
  fill_k<<<1024, 256, 0, stream>>>(eidx, mode, cursor, csr, E);

  // f16 conversions (inputs are L2/L3 resident afterwards)
  cast_k<<<1024, 256, 0, stream>>>(x, xh, N * 128 / 4);
  tcast_k<<<64, 256, 0, stream>>>(W1, W1t);
  tcast_k<<<64, 256, 0, stream>>>(W2, W2t);
  cast_k<<<64, 256, 0, stream>>>(Wih, Wih_h, 65536 / 4);
  cast_k<<<8, 256, 0, stream>>>(Wlin, Wlin_h, 8192 / 4);

  const int gx = (N + 63) / 64;
  const int ga = (N + 15) / 16;  // agg: 16 nodes per 256-thread block
  // conv1: Ph = f16((x@W1)*dinv) ; Qh = f16(relu(agg(Ph)*dinv + b1))
  mgemm_k<0><<<dim3(gx, 2), 256, 0, stream>>>(xh, W1t, nullptr, Ph, 128, dinv,
                                              nullptr, nullptr, N);
  agg_k<<<ga, 256, 0, stream>>>(Ph, off, cnt, csr, dinv, b1, Qh, N);
  // conv2
  mgemm_k<0><<<dim3(gx, 2), 256, 0, stream>>>(Qh, W2t, nullptr, Ph, 128, dinv,
                                              nullptr, nullptr, N);
  agg_k<<<ga, 256, 0, stream>>>(Ph, off, cnt, csr, dinv, b2, Qh, N);
  // x_proj = Qh @ Wih^T + (bih + bhh) -> f16
  mgemm_k<1><<<dim3(gx, 8), 256, 0, stream>>>(Qh, Wih_h, nullptr, XP, 512,
                                              nullptr, bih, bhh, N);
  // chunked LSTM
  const int L = (N + NCHUNK - 1) / NCHUNK;
  lstm_k<<<NCHUNK, 512, 0, stream>>>(XP, Whh, HLh, N, L);
  // final linear: out = HL @ Wlin^T + blin (f32 out)
  mgemm_k<2><<<dim3(gx, 1), 256, 0, stream>>>(HLh, Wlin_h, out, nullptr, 64,
                                              nullptr, blin, nullptr, N);
}

// Round 12
// 775.411 us; speedup vs baseline: 1.1316x; 1.1316x over previous
//
#include <hip/hip_runtime.h>
#include <hip/hip_fp16.h>

#define HID   128
#define WARM  80
#define NCHUNK 512

// ---------------- graph prep ----------------

__global__ void detect_k(const int* __restrict__ e, int* __restrict__ mode) {
  if (threadIdx.x == 0 && blockIdx.x == 0) {
    int z = 0;
#pragma unroll
    for (int k = 0; k < 8; ++k) z |= e[2 * k + 1];
    *mode = (z == 0) ? 1 : 0;  // 1 = int64, 0 = int32
  }
}

__global__ void deg_k(const int* __restrict__ e, const int* __restrict__ mode,
                      int* __restrict__ cnt, int E) {
  const int m = *mode;
  for (int i = blockIdx.x * 256 + threadIdx.x; i < E; i += gridDim.x * 256) {
    int d = m ? e[2 * (E + i)] : e[E + i];
    atomicAdd(&cnt[d], 1);
  }
}

__global__ void fill_k(const int* __restrict__ e, const int* __restrict__ mode,
                       int* __restrict__ cursor, int* __restrict__ csr, int E) {
  const int m = *mode;
  for (int i = blockIdx.x * 256 + threadIdx.x; i < E; i += gridDim.x * 256) {
    int s = m ? e[2 * i] : e[i];
    int d = m ? e[2 * (E + i)] : e[E + i];
    int p = atomicAdd(&cursor[d], 1);
    csr[p] = s;
  }
}

// ---------------- parallel scan (3 kernels, integer-exact) ----------------
__global__ __launch_bounds__(1024) void scan1_k(const int* __restrict__ cnt,
                                                int* __restrict__ off,
                                                int* __restrict__ tot, int n) {
  __shared__ int wsum[16];
  const int tid = threadIdx.x, lane = tid & 63, wv = tid >> 6;
  const int i = blockIdx.x * 1024 + tid;
  int v = (i < n) ? cnt[i] : 0;
  int x = v;
#pragma unroll
  for (int s = 1; s < 64; s <<= 1) {
    int y = __shfl_up(x, (unsigned)s, 64);
    if (lane >= s) x += y;
  }
  if (lane == 63) wsum[wv] = x;
  __syncthreads();
  int wpre = 0, t = 0;
#pragma unroll
  for (int q = 0; q < 16; ++q) {
    int s = wsum[q];
    t += s;
    if (q < wv) wpre += s;
  }
  if (i < n) off[i] = wpre + x - v;
  if (tid == 0) tot[blockIdx.x] = t;
}

__global__ void scan2_k(int* __restrict__ tot, int nb) {
  const int lane = threadIdx.x & 63;
  int v = (lane < nb) ? tot[lane] : 0;
  int x = v;
#pragma unroll
  for (int s = 1; s < 64; s <<= 1) {
    int y = __shfl_up(x, (unsigned)s, 64);
    if (lane >= s) x += y;
  }
  if (lane < nb) tot[lane] = x - v;
}

__global__ void scan3_k(int* __restrict__ off, const int* __restrict__ tot,
                        int* __restrict__ cursor, const int* __restrict__ cnt,
                        float* __restrict__ dinv, int n) {
  const int i = blockIdx.x * 256 + threadIdx.x;
  if (i < n) {
    int o = off[i] + tot[i >> 10];
    off[i] = o;
    cursor[i] = o;
    dinv[i] = rsqrtf((float)(cnt[i] + 1));
  }
}

// ---------------- f32 -> f16 conversion helpers ----------------
struct half4s { __half2 a, b; };

__global__ void cast_k(const float* __restrict__ src, __half* __restrict__ dst,
                       int n4) {
  for (int i = blockIdx.x * 256 + threadIdx.x; i < n4; i += gridDim.x * 256) {
    float4 v = ((const float4*)src)[i];
    half4s h;
    h.a = __floats2half2_rn(v.x, v.y);
    h.b = __floats2half2_rn(v.z, v.w);
    ((half4s*)dst)[i] = h;
  }
}

// transpose+cast a 128x128 f32 matrix -> f16 [col][row]
__global__ void tcast_k(const float* __restrict__ src, __half* __restrict__ dst) {
  const int idx = blockIdx.x * 256 + threadIdx.x;  // 16384 threads
  const int r = idx >> 7, c = idx & 127;
  dst[(c << 7) + r] = __float2half(src[idx]);
}

// ---------------- MFMA GEMM: C[M x N] = A[M x 128] @ B, K=128 ----------------
// validated round 10: layout per guide §3, no LDS (operands L2/L3-resident).
// Grid is (n-blocks, m-strips) with n FASTEST so the consecutive blocks that
// re-read the same A m-strip run back-to-back -> A stays L2-hot (the strip
// array is 12.8MB, bigger than one XCD's 4MB L2, so temporal locality matters).
typedef _Float16 f16x8 __attribute__((ext_vector_type(8)));
typedef float f32x4 __attribute__((ext_vector_type(4)));

template <int EPI>
__global__ __launch_bounds__(256) void mgemm_k(
    const __half* __restrict__ A, const __half* __restrict__ Bt,
    float* __restrict__ Of, __half* __restrict__ Oh, int ostride,
    const float* __restrict__ dinv, const float* __restrict__ bias0,
    const float* __restrict__ bias1, int M) {
  const int tid = threadIdx.x;
  const int wv = tid >> 6, lane = tid & 63;
  const int m0 = blockIdx.y * 64 + wv * 16;  // m-strip: slow grid dim
  const int n0 = blockIdx.x * 64;            // n-block: fast grid dim
  const int lrow = lane & 15, lk = lane >> 4;

  int am = m0 + lrow;
  if (am >= M) am = M - 1;
  const __half* ap = A + (long)am * 128 + lk * 8;
  const __half* bp = Bt + (long)(n0 + lrow) * 128 + lk * 8;

  f16x8 afr[4];
#pragma unroll
  for (int s = 0; s < 4; ++s) afr[s] = *(const f16x8*)(ap + s * 32);

  f32x4 acc[4];
#pragma unroll
  for (int nb = 0; nb < 4; ++nb) {
    f32x4 c = {0.f, 0.f, 0.f, 0.f};
#pragma unroll
    for (int s = 0; s < 4; ++s) {
      f16x8 bfr = *(const f16x8*)(bp + (long)nb * 16 * 128 + s * 32);
      c = __builtin_amdgcn_mfma_f32_16x16x32_f16(afr[s], bfr, c, 0, 0, 0);
    }
    acc[nb] = c;
  }

  const int crow0 = m0 + lk * 4;
  const int ccol = n0 + lrow;
#pragma unroll
  for (int j = 0; j < 4; ++j) {
    const int row = crow0 + j;
    if (row >= M) continue;
    if (EPI == 0) {
      const float d = dinv[row];
#pragma unroll
      for (int nb = 0; nb < 4; ++nb)
        Oh[(long)row * ostride + ccol + nb * 16] = __float2half(acc[nb][j] * d);
    } else if (EPI == 1) {
#pragma unroll
      for (int nb = 0; nb < 4; ++nb) {
        const int n = ccol + nb * 16;
        Oh[(long)row * ostride + n] =
            __float2half(acc[nb][j] + bias0[n] + bias1[n]);
      }
    } else {
#pragma unroll
      for (int nb = 0; nb < 4; ++nb) {
        const int n = ccol + nb * 16;
        Of[(long)row * ostride + n] = acc[nb][j] + bias0[n];
      }
    }
  }
}

// ---------------- aggregation: 4 nodes per wave, 16B loads ----------------
// OUT[i] = f16(relu(dinv[i]*(sum HS[src] + HS[i]) + bias)), f32 accum.
// 16 lanes x half8 (16B) per 256B row; per-channel order identical to before.
__global__ __launch_bounds__(256) void agg_k(
    const __half* __restrict__ HS, const int* __restrict__ off,
    const int* __restrict__ cnt, const int* __restrict__ csr,
    const float* __restrict__ dinv, const float* __restrict__ bias,
    __half* __restrict__ OUT, int Nn) {
  const int w = (blockIdx.x * 256 + threadIdx.x) >> 6;
  const int lane = threadIdx.x & 63;
  const int node = w * 4 + (lane >> 4);
  if (node >= Nn) return;
  const int f = (lane & 15) * 8;  // 8 halfs per lane
  const int o0 = off[node];
  const int ce = cnt[node];
  float acc[8];
  {
    uint4 u = *(const uint4*)&HS[(long)node * 128 + f];
    const __half2* hp = (const __half2*)&u;
#pragma unroll
    for (int q = 0; q < 4; ++q) {
      float2 t = __half22float2(hp[q]);
      acc[2 * q] = t.x;
      acc[2 * q + 1] = t.y;
    }
  }
  auto addrow = [&](uint4 u) {
    const __half2* hp = (const __half2*)&u;
#pragma unroll
    for (int q = 0; q < 4; ++q) {
      float2 t = __half22float2(hp[q]);
      acc[2 * q] += t.x;
      acc[2 * q + 1] += t.y;
    }
  };
  int e = 0;
  for (; e + 4 <= ce; e += 4) {
    int s0 = csr[o0 + e + 0];
    int s1 = csr[o0 + e + 1];
    int s2 = csr[o0 + e + 2];
    int s3 = csr[o0 + e + 3];
    uint4 u0 = *(const uint4*)&HS[(long)s0 * 128 + f];
    uint4 u1 = *(const uint4*)&HS[(long)s1 * 128 + f];
    uint4 u2 = *(const uint4*)&HS[(long)s2 * 128 + f];
    uint4 u3 = *(const uint4*)&HS[(long)s3 * 128 + f];
    addrow(u0);
    addrow(u1);
    addrow(u2);
    addrow(u3);
  }
  for (; e < ce; ++e) {
    uint4 u = *(const uint4*)&HS[(long)csr[o0 + e] * 128 + f];
    addrow(u);
  }
  float d = dinv[node];
  __half2 o[4];
#pragma unroll
  for (int q = 0; q < 4; ++q) {
    float bx = bias[f + 2 * q], by = bias[f + 2 * q + 1];
    o[q] = __floats2half2_rn(fmaxf(acc[2 * q] * d + bx, 0.f),
                             fmaxf(acc[2 * q + 1] * d + by, 0.f));
  }
  *(uint4*)&OUT[(long)node * 128 + f] = *(uint4*)o;
}

// ---------------- chunked LSTM: wave-local gates, 1 barrier/step ----------------
// EXACT round-10 validated kernel (269µs, 64 VGPR, occ 39%). Round-11's
// "zero-cvt" wf[128]-in-registers variant REGRESSED to 348µs + a 30ms
// scratch-first-touch dispatch: the compiler kept VGPR=84 and demoted the
// weight array to scratch. Do not reintroduce without VGPR_Count verification.
// Inline-asm v_dot2_f32_f16 FAILED numerically twice (rounds 6,7) — keep out.
// WARM=80 + builtin path validated (rounds 9,10). NCHUNK=512 optimum
// (issue-bound, T ∝ N + WARM*NCHUNK; 2 blocks/CU).
typedef _Float16 h2f __attribute__((ext_vector_type(2)));

__global__ __launch_bounds__(512, 4) void lstm_k(
    const __half* __restrict__ XP, const float* __restrict__ Whh,
    __half* __restrict__ HL, int N, int L) {
  __shared__ __half hbuf[2][128];
  const int tid = threadIdx.x;
  const int w = tid >> 6, lane = tid & 63;
  const int gate = lane >> 4, sub = lane & 15;
  const int jj = w * 16 + sub;    // 0..127 hidden channel
  const int r = gate * 128 + jj;  // row in [512] gate matrix
  const int ch = blockIdx.x;
  long start = (long)ch * L;
  if (start >= N) return;  // uniform per block
  long t1 = start + L;
  if (t1 > N) t1 = N;
  long t0 = start - WARM;
  if (t0 < 0) t0 = 0;

  // W_hh row r packed to f16 pairs: 64 VGPRs
  h2f wh[64];
  {
    const float2* wp = (const float2*)(Whh + (long)r * 128);
#pragma unroll
    for (int i = 0; i < 64; ++i) {
      float2 f = wp[i];
      h2f v;
      v.x = (_Float16)f.x;
      v.y = (_Float16)f.y;
      wh[i] = v;
    }
  }

  if (tid < 128) {
    hbuf[0][tid] = __float2half(0.f);
    hbuf[1][tid] = __float2half(0.f);
  }
  float cst = 0.f;
  const float m = (gate == 2) ? 2.f : 1.f;  // tanh(x) = 2*sigmoid(2x)-1
  const float mb = 1.f - m;
  __syncthreads();

  int p = 0;
  float xpv = __half2float(XP[t0 * 512 + r]);
  for (long t = t0; t < t1; ++t) {
    float xpn = (t + 1 < t1) ? __half2float(XP[(t + 1) * 512 + r]) : 0.f;
    float a0 = 0.f, a1 = 0.f, a2 = 0.f, a3 = 0.f;
    const uint4* hb = (const uint4*)&hbuf[p][0];
#pragma unroll
    for (int i = 0; i < 16; ++i) {
      uint4 u = hb[i];  // 8 halfs, LDS broadcast (same addr all lanes)
      h2f b0 = __builtin_bit_cast(h2f, u.x);
      h2f b1 = __builtin_bit_cast(h2f, u.y);
      h2f b2 = __builtin_bit_cast(h2f, u.z);
      h2f b3 = __builtin_bit_cast(h2f, u.w);
#if __has_builtin(__builtin_amdgcn_fdot2)
      a0 = __builtin_amdgcn_fdot2(wh[4 * i + 0], b0, a0, false);
      a1 = __builtin_amdgcn_fdot2(wh[4 * i + 1], b1, a1, false);
      a2 = __builtin_amdgcn_fdot2(wh[4 * i + 2], b2, a2, false);
      a3 = __builtin_amdgcn_fdot2(wh[4 * i + 3], b3, a3, false);
#else
      a0 += (float)wh[4 * i + 0].x * (float)b0.x + (float)wh[4 * i + 0].y * (float)b0.y;
      a1 += (float)wh[4 * i + 1].x * (float)b1.x + (float)wh[4 * i + 1].y * (float)b1.y;
      a2 += (float)wh[4 * i + 2].x * (float)b2.x + (float)wh[4 * i + 2].y * (float)b2.y;
      a3 += (float)wh[4 * i + 3].x * (float)b3.x + (float)wh[4 * i + 3].y * (float)b3.y;
#endif
    }
    float acc = xpv + ((a0 + a1) + (a2 + a3));
    float y = 1.f / (1.f + __expf(-m * acc));
    float act = fmaf(m, y, mb);  // sigmoid for i,f,o; tanh for g
    float gi = __shfl(act, sub + 0, 64);
    float gf = __shfl(act, sub + 16, 64);
    float gg = __shfl(act, sub + 32, 64);
    float go = __shfl(act, sub + 48, 64);
    cst = fmaf(gf, cst, gi * gg);
    float e = __expf(2.f * cst);
    float th = 1.f - 2.f / (e + 1.f);
    float h = go * th;
    if (gate == 0) {
      __half hh = __float2half(h);
      hbuf[p ^ 1][jj] = hh;
      if (t >= start) HL[t * 128 + jj] = hh;
    }
    __syncthreads();
    p ^= 1;
    xpv = xpn;
  }
}

// ---------------- launch ----------------
extern "C" void kernel_launch(void* const* d_in, const int* in_sizes, int n_in,
                              void* d_out, int out_size, void* d_ws,
                              size_t ws_size, hipStream_t stream) {
  const float* x = (const float*)d_in[0];
  const int* eidx = (const int*)d_in[1];
  const float* W1 = (const float*)d_in[3];
  const float* b1 = (const float*)d_in[4];
  const float* W2 = (const float*)d_in[5];
  const float* b2 = (const float*)d_in[6];
  const float* Wih = (const float*)d_in[7];
  const float* Whh = (const float*)d_in[8];
  const float* bih = (const float*)d_in[9];
  const float* bhh = (const float*)d_in[10];
  const float* Wlin = (const float*)d_in[11];
  const float* blin = (const float*)d_in[12];
  float* out = (float*)d_out;

  const int N = in_sizes[0] / 128;
  const int E = in_sizes[1] / 2;

  size_t cur = 0;
  auto alloc = [&](size_t nbytes) -> char* {
    char* p = (char*)d_ws + cur;
    cur += (nbytes + 255) & ~(size_t)255;
    return p;
  };
  int* mode = (int*)alloc(4);
  int* cnt = (int*)alloc((size_t)N * 4);
  int* off = (int*)alloc((size_t)N * 4);
  int* cursor = (int*)alloc((size_t)N * 4);
  float* dinv = (float*)alloc((size_t)N * 4);
  int* tot = (int*)alloc(64 * 4);
  int* csr = (int*)alloc((size_t)E * 4);
  __half* xh = (__half*)alloc((size_t)N * 128 * 2);
  __half* W1t = (__half*)alloc(16384 * 2);
  __half* W2t = (__half*)alloc(16384 * 2);
  __half* Wih_h = (__half*)alloc(65536 * 2);
  __half* Wlin_h = (__half*)alloc(8192 * 2);
  __half* Ph = (__half*)alloc((size_t)N * 128 * 2);
  __half* Qh = (__half*)alloc((size_t)N * 128 * 2);
  __half* XP = (__half*)alloc((size_t)N * 512 * 2);
  __half* HLh = (__half*)alloc((size_t)N * 128 * 2);

  hipMemsetAsync(cnt, 0, (size_t)N * 4, stream);
  detect_k<<<1, 64, 0, stream>>>(eidx, mode);
  deg_k<<<1024, 256, 0, stream>>>(eidx, mode, cnt, E);
  const int nb = (N + 1023) / 1024;
  scan1_k<<<nb, 1024, 0, stream>>>(cnt, off, tot, N);
  scan2_k<<<1, 64, 0, stream>>>(tot, nb);
  scan3_k<<<(N + 255) / 256, 256, 0, stream>>>(off, tot, cursor, cnt, dinv, N);
  fill_k<<<1024, 256, 0, stream>>>(eidx, mode, cursor, csr, E);

  // f16 conversions (inputs are L2/L3 resident afterwards)
  cast_k<<<1024, 256, 0, stream>>>(x, xh, N * 128 / 4);
  tcast_k<<<64, 256, 0, stream>>>(W1, W1t);
  tcast_k<<<64, 256, 0, stream>>>(W2, W2t);
  cast_k<<<64, 256, 0, stream>>>(Wih, Wih_h, 65536 / 4);
  cast_k<<<8, 256, 0, stream>>>(Wlin, Wlin_h, 8192 / 4);

  const int gx = (N + 63) / 64;
  const int ga = (N + 15) / 16;  // agg: 16 nodes per 256-thread block
  // conv1: Ph = f16((x@W1)*dinv) ; Qh = f16(relu(agg(Ph)*dinv + b1))
  mgemm_k<0><<<dim3(2, gx), 256, 0, stream>>>(xh, W1t, nullptr, Ph, 128, dinv,
                                              nullptr, nullptr, N);
  agg_k<<<ga, 256, 0, stream>>>(Ph, off, cnt, csr, dinv, b1, Qh, N);
  // conv2
  mgemm_k<0><<<dim3(2, gx), 256, 0, stream>>>(Qh, W2t, nullptr, Ph, 128, dinv,
                                              nullptr, nullptr, N);
  agg_k<<<ga, 256, 0, stream>>>(Ph, off, cnt, csr, dinv, b2, Qh, N);
  // x_proj = Qh @ Wih^T + (bih + bhh) -> f16
  mgemm_k<1><<<dim3(8, gx), 256, 0, stream>>>(Qh, Wih_h, nullptr, XP, 512,
                                              nullptr, bih, bhh, N);
  // chunked LSTM
  const int L = (N + NCHUNK - 1) / NCHUNK;
  lstm_k<<<NCHUNK, 512, 0, stream>>>(XP, Whh, HLh, N, L);
  // final linear: out = HL @ Wlin^T + blin (f32 out)
  mgemm_k<2><<<dim3(1, gx), 256, 0, stream>>>(HLh, Wlin_h, out, nullptr, 64,
                                              nullptr, blin, nullptr, N);
}

// Round 13
// 761.207 us; speedup vs baseline: 1.1527x; 1.0187x over previous
//
#include <hip/hip_runtime.h>
#include <hip/hip_fp16.h>

#define HID   128
#define WARM  80
#define NCHUNK 512

// ---------------- graph prep ----------------

__global__ void detect_k(const int* __restrict__ e, int* __restrict__ mode) {
  if (threadIdx.x == 0 && blockIdx.x == 0) {
    int z = 0;
#pragma unroll
    for (int k = 0; k < 8; ++k) z |= e[2 * k + 1];
    *mode = (z == 0) ? 1 : 0;  // 1 = int64, 0 = int32
  }
}

__global__ void deg_k(const int* __restrict__ e, const int* __restrict__ mode,
                      int* __restrict__ cnt, int E) {
  const int m = *mode;
  for (int i = blockIdx.x * 256 + threadIdx.x; i < E; i += gridDim.x * 256) {
    int d = m ? e[2 * (E + i)] : e[E + i];
    atomicAdd(&cnt[d], 1);
  }
}

__global__ void fill_k(const int* __restrict__ e, const int* __restrict__ mode,
                       int* __restrict__ cursor, int* __restrict__ csr, int E) {
  const int m = *mode;
  for (int i = blockIdx.x * 256 + threadIdx.x; i < E; i += gridDim.x * 256) {
    int s = m ? e[2 * i] : e[i];
    int d = m ? e[2 * (E + i)] : e[E + i];
    int p = atomicAdd(&cursor[d], 1);
    csr[p] = s;
  }
}

// ---------------- parallel scan (3 kernels, integer-exact) ----------------
__global__ __launch_bounds__(1024) void scan1_k(const int* __restrict__ cnt,
                                                int* __restrict__ off,
                                                int* __restrict__ tot, int n) {
  __shared__ int wsum[16];
  const int tid = threadIdx.x, lane = tid & 63, wv = tid >> 6;
  const int i = blockIdx.x * 1024 + tid;
  int v = (i < n) ? cnt[i] : 0;
  int x = v;
#pragma unroll
  for (int s = 1; s < 64; s <<= 1) {
    int y = __shfl_up(x, (unsigned)s, 64);
    if (lane >= s) x += y;
  }
  if (lane == 63) wsum[wv] = x;
  __syncthreads();
  int wpre = 0, t = 0;
#pragma unroll
  for (int q = 0; q < 16; ++q) {
    int s = wsum[q];
    t += s;
    if (q < wv) wpre += s;
  }
  if (i < n) off[i] = wpre + x - v;
  if (tid == 0) tot[blockIdx.x] = t;
}

__global__ void scan2_k(int* __restrict__ tot, int nb) {
  const int lane = threadIdx.x & 63;
  int v = (lane < nb) ? tot[lane] : 0;
  int x = v;
#pragma unroll
  for (int s = 1; s < 64; s <<= 1) {
    int y = __shfl_up(x, (unsigned)s, 64);
    if (lane >= s) x += y;
  }
  if (lane < nb) tot[lane] = x - v;
}

__global__ void scan3_k(int* __restrict__ off, const int* __restrict__ tot,
                        int* __restrict__ cursor, const int* __restrict__ cnt,
                        float* __restrict__ dinv, int n) {
  const int i = blockIdx.x * 256 + threadIdx.x;
  if (i < n) {
    int o = off[i] + tot[i >> 10];
    off[i] = o;
    cursor[i] = o;
    dinv[i] = rsqrtf((float)(cnt[i] + 1));
  }
}

// ---------------- fused weight cast/transpose-cast (one launch) ----------------
// layout: [0,16384) W1 transpose-cast; [16384,32768) W2 t-cast;
//         [32768,98304) Wih cast; [98304,106496) Wlin cast
__global__ void wprep_k(const float* __restrict__ W1, const float* __restrict__ W2,
                        const float* __restrict__ Wih, const float* __restrict__ Wlin,
                        __half* __restrict__ W1t, __half* __restrict__ W2t,
                        __half* __restrict__ Wih_h, __half* __restrict__ Wlin_h) {
  int idx = blockIdx.x * 256 + threadIdx.x;
  if (idx < 16384) {
    int r = idx >> 7, c = idx & 127;
    W1t[(c << 7) + r] = __float2half(W1[idx]);
  } else if (idx < 32768) {
    int j = idx - 16384;
    int r = j >> 7, c = j & 127;
    W2t[(c << 7) + r] = __float2half(W2[j]);
  } else if (idx < 98304) {
    int j = idx - 32768;
    Wih_h[j] = __float2half(Wih[j]);
  } else if (idx < 106496) {
    int j = idx - 98304;
    Wlin_h[j] = __float2half(Wlin[j]);
  }
}

// ---------------- MFMA GEMM: C[M x N] = A[M x 128] @ B, K=128 ----------------
// validated round 10: layout per guide §3, no LDS (operands L2/L3-resident).
// AF32: read f32 A directly, cvt fragments in-register (same rn rounding as
// the old cast_k pass -> bit-identical f16 values, saves a 38MB cast pass).
typedef _Float16 f16x8 __attribute__((ext_vector_type(8)));
typedef float f32x4 __attribute__((ext_vector_type(4)));

template <int EPI, bool AF32>
__global__ __launch_bounds__(256) void mgemm_k(
    const void* __restrict__ Av, const __half* __restrict__ Bt,
    float* __restrict__ Of, __half* __restrict__ Oh, int ostride,
    const float* __restrict__ dinv, const float* __restrict__ bias0,
    const float* __restrict__ bias1, int M) {
  const int tid = threadIdx.x;
  const int wv = tid >> 6, lane = tid & 63;
  const int m0 = blockIdx.y * 64 + wv * 16;
  const int n0 = blockIdx.x * 64;
  const int lrow = lane & 15, lk = lane >> 4;

  int am = m0 + lrow;
  if (am >= M) am = M - 1;
  const __half* bp = Bt + (long)(n0 + lrow) * 128 + lk * 8;

  f16x8 afr[4];
  if (AF32) {
    const float* ap = (const float*)Av + (long)am * 128 + lk * 8;
#pragma unroll
    for (int s = 0; s < 4; ++s) {
      float4 v0 = *(const float4*)(ap + s * 32);
      float4 v1 = *(const float4*)(ap + s * 32 + 4);
      f16x8 t;
      t[0] = (_Float16)v0.x; t[1] = (_Float16)v0.y;
      t[2] = (_Float16)v0.z; t[3] = (_Float16)v0.w;
      t[4] = (_Float16)v1.x; t[5] = (_Float16)v1.y;
      t[6] = (_Float16)v1.z; t[7] = (_Float16)v1.w;
      afr[s] = t;
    }
  } else {
    const __half* ap = (const __half*)Av + (long)am * 128 + lk * 8;
#pragma unroll
    for (int s = 0; s < 4; ++s) afr[s] = *(const f16x8*)(ap + s * 32);
  }

  f32x4 acc[4];
#pragma unroll
  for (int nb = 0; nb < 4; ++nb) {
    f32x4 c = {0.f, 0.f, 0.f, 0.f};
#pragma unroll
    for (int s = 0; s < 4; ++s) {
      f16x8 bfr = *(const f16x8*)(bp + (long)nb * 16 * 128 + s * 32);
      c = __builtin_amdgcn_mfma_f32_16x16x32_f16(afr[s], bfr, c, 0, 0, 0);
    }
    acc[nb] = c;
  }

  const int crow0 = m0 + lk * 4;
  const int ccol = n0 + lrow;
#pragma unroll
  for (int j = 0; j < 4; ++j) {
    const int row = crow0 + j;
    if (row >= M) continue;
    if (EPI == 0) {
      const float d = dinv[row];
#pragma unroll
      for (int nb = 0; nb < 4; ++nb)
        Oh[(long)row * ostride + ccol + nb * 16] = __float2half(acc[nb][j] * d);
    } else if (EPI == 1) {
#pragma unroll
      for (int nb = 0; nb < 4; ++nb) {
        const int n = ccol + nb * 16;
        Oh[(long)row * ostride + n] =
            __float2half(acc[nb][j] + bias0[n] + bias1[n]);
      }
    } else {
#pragma unroll
      for (int nb = 0; nb < 4; ++nb) {
        const int n = ccol + nb * 16;
        Of[(long)row * ostride + n] = acc[nb][j] + bias0[n];
      }
    }
  }
}

// ---------------- aggregation: 4 nodes/wave, 8-edge deep gather pipeline -----
// OUT[i] = f16(relu(dinv[i]*(sum HS[src] + HS[i]) + bias)), f32 accum.
// 16 lanes x half8 (16B) per 256B row. 8 indices loaded, then 8 gathers
// issued back-to-back (8-deep MLP), then accumulated IN EDGE ORDER ->
// bit-identical sums to the 4/1-unroll versions.
__global__ __launch_bounds__(256) void agg_k(
    const __half* __restrict__ HS, const int* __restrict__ off,
    const int* __restrict__ cnt, const int* __restrict__ csr,
    const float* __restrict__ dinv, const float* __restrict__ bias,
    __half* __restrict__ OUT, int Nn) {
  const int w = (blockIdx.x * 256 + threadIdx.x) >> 6;
  const int lane = threadIdx.x & 63;
  const int node = w * 4 + (lane >> 4);
  if (node >= Nn) return;
  const int f = (lane & 15) * 8;  // 8 halfs per lane
  const int o0 = off[node];
  const int ce = cnt[node];
  float acc[8];
  {
    uint4 u = *(const uint4*)&HS[(long)node * 128 + f];
    const __half2* hp = (const __half2*)&u;
#pragma unroll
    for (int q = 0; q < 4; ++q) {
      float2 t = __half22float2(hp[q]);
      acc[2 * q] = t.x;
      acc[2 * q + 1] = t.y;
    }
  }
  auto addrow = [&](uint4 u) {
    const __half2* hp = (const __half2*)&u;
#pragma unroll
    for (int q = 0; q < 4; ++q) {
      float2 t = __half22float2(hp[q]);
      acc[2 * q] += t.x;
      acc[2 * q + 1] += t.y;
    }
  };
  int e = 0;
  for (; e + 8 <= ce; e += 8) {
    int idx[8];
#pragma unroll
    for (int j = 0; j < 8; ++j) idx[j] = csr[o0 + e + j];
    uint4 u[8];
#pragma unroll
    for (int j = 0; j < 8; ++j)
      u[j] = *(const uint4*)&HS[(long)idx[j] * 128 + f];
#pragma unroll
    for (int j = 0; j < 8; ++j) addrow(u[j]);
  }
  for (; e + 4 <= ce; e += 4) {
    int i0 = csr[o0 + e + 0], i1 = csr[o0 + e + 1];
    int i2 = csr[o0 + e + 2], i3 = csr[o0 + e + 3];
    uint4 u0 = *(const uint4*)&HS[(long)i0 * 128 + f];
    uint4 u1 = *(const uint4*)&HS[(long)i1 * 128 + f];
    uint4 u2 = *(const uint4*)&HS[(long)i2 * 128 + f];
    uint4 u3 = *(const uint4*)&HS[(long)i3 * 128 + f];
    addrow(u0);
    addrow(u1);
    addrow(u2);
    addrow(u3);
  }
  for (; e < ce; ++e) {
    uint4 u = *(const uint4*)&HS[(long)csr[o0 + e] * 128 + f];
    addrow(u);
  }
  float d = dinv[node];
  __half2 o[4];
#pragma unroll
  for (int q = 0; q < 4; ++q) {
    float bx = bias[f + 2 * q], by = bias[f + 2 * q + 1];
    o[q] = __floats2half2_rn(fmaxf(acc[2 * q] * d + bx, 0.f),
                             fmaxf(acc[2 * q + 1] * d + by, 0.f));
  }
  *(uint4*)&OUT[(long)node * 128 + f] = *(uint4*)o;
}

// ---------------- chunked LSTM: wave-local gates, 1 barrier/step ----------------
// EXACT round-10/12 validated kernel (269µs, 64 VGPR, occ 39%). Round-11's
// wf[128]-in-registers variant REGRESSED (scratch demotion, VGPR=84, 348µs +
// 30ms first-touch). Inline-asm v_dot2_f32_f16 FAILED numerically (r6,7).
// WARM=80 + builtin path validated (r9,10,12). NCHUNK=512 optimum (2 bl/CU).
typedef _Float16 h2f __attribute__((ext_vector_type(2)));

__global__ __launch_bounds__(512, 4) void lstm_k(
    const __half* __restrict__ XP, const float* __restrict__ Whh,
    __half* __restrict__ HL, int N, int L) {
  __shared__ __half hbuf[2][128];
  const int tid = threadIdx.x;
  const int w = tid >> 6, lane = tid & 63;
  const int gate = lane >> 4, sub = lane & 15;
  const int jj = w * 16 + sub;    // 0..127 hidden channel
  const int r = gate * 128 + jj;  // row in [512] gate matrix
  const int ch = blockIdx.x;
  long start = (long)ch * L;
  if (start >= N) return;  // uniform per block
  long t1 = start + L;
  if (t1 > N) t1 = N;
  long t0 = start - WARM;
  if (t0 < 0) t0 = 0;

  // W_hh row r packed to f16 pairs: 64 VGPRs
  h2f wh[64];
  {
    const float2* wp = (const float2*)(Whh + (long)r * 128);
#pragma unroll
    for (int i = 0; i < 64; ++i) {
      float2 f = wp[i];
      h2f v;
      v.x = (_Float16)f.x;
      v.y = (_Float16)f.y;
      wh[i] = v;
    }
  }

  if (tid < 128) {
    hbuf[0][tid] = __float2half(0.f);
    hbuf[1][tid] = __float2half(0.f);
  }
  float cst = 0.f;
  const float m = (gate == 2) ? 2.f : 1.f;  // tanh(x) = 2*sigmoid(2x)-1
  const float mb = 1.f - m;
  __syncthreads();

  int p = 0;
  float xpv = __half2float(XP[t0 * 512 + r]);
  for (long t = t0; t < t1; ++t) {
    float xpn = (t + 1 < t1) ? __half2float(XP[(t + 1) * 512 + r]) : 0.f;
    float a0 = 0.f, a1 = 0.f, a2 = 0.f, a3 = 0.f;
    const uint4* hb = (const uint4*)&hbuf[p][0];
#pragma unroll
    for (int i = 0; i < 16; ++i) {
      uint4 u = hb[i];  // 8 halfs, LDS broadcast (same addr all lanes)
      h2f b0 = __builtin_bit_cast(h2f, u.x);
      h2f b1 = __builtin_bit_cast(h2f, u.y);
      h2f b2 = __builtin_bit_cast(h2f, u.z);
      h2f b3 = __builtin_bit_cast(h2f, u.w);
#if __has_builtin(__builtin_amdgcn_fdot2)
      a0 = __builtin_amdgcn_fdot2(wh[4 * i + 0], b0, a0, false);
      a1 = __builtin_amdgcn_fdot2(wh[4 * i + 1], b1, a1, false);
      a2 = __builtin_amdgcn_fdot2(wh[4 * i + 2], b2, a2, false);
      a3 = __builtin_amdgcn_fdot2(wh[4 * i + 3], b3, a3, false);
#else
      a0 += (float)wh[4 * i + 0].x * (float)b0.x + (float)wh[4 * i + 0].y * (float)b0.y;
      a1 += (float)wh[4 * i + 1].x * (float)b1.x + (float)wh[4 * i + 1].y * (float)b1.y;
      a2 += (float)wh[4 * i + 2].x * (float)b2.x + (float)wh[4 * i + 2].y * (float)b2.y;
      a3 += (float)wh[4 * i + 3].x * (float)b3.x + (float)wh[4 * i + 3].y * (float)b3.y;
#endif
    }
    float acc = xpv + ((a0 + a1) + (a2 + a3));
    float y = 1.f / (1.f + __expf(-m * acc));
    float act = fmaf(m, y, mb);  // sigmoid for i,f,o; tanh for g
    float gi = __shfl(act, sub + 0, 64);
    float gf = __shfl(act, sub + 16, 64);
    float gg = __shfl(act, sub + 32, 64);
    float go = __shfl(act, sub + 48, 64);
    cst = fmaf(gf, cst, gi * gg);
    float e = __expf(2.f * cst);
    float th = 1.f - 2.f / (e + 1.f);
    float h = go * th;
    if (gate == 0) {
      __half hh = __float2half(h);
      hbuf[p ^ 1][jj] = hh;
      if (t >= start) HL[t * 128 + jj] = hh;
    }
    __syncthreads();
    p ^= 1;
    xpv = xpn;
  }
}

// ---------------- launch ----------------
extern "C" void kernel_launch(void* const* d_in, const int* in_sizes, int n_in,
                              void* d_out, int out_size, void* d_ws,
                              size_t ws_size, hipStream_t stream) {
  const float* x = (const float*)d_in[0];
  const int* eidx = (const int*)d_in[1];
  const float* W1 = (const float*)d_in[3];
  const float* b1 = (const float*)d_in[4];
  const float* W2 = (const float*)d_in[5];
  const float* b2 = (const float*)d_in[6];
  const float* Wih = (const float*)d_in[7];
  const float* Whh = (const float*)d_in[8];
  const float* bih = (const float*)d_in[9];
  const float* bhh = (const float*)d_in[10];
  const float* Wlin = (const float*)d_in[11];
  const float* blin = (const float*)d_in[12];
  float* out = (float*)d_out;

  const int N = in_sizes[0] / 128;
  const int E = in_sizes[1] / 2;

  size_t cur = 0;
  auto alloc = [&](size_t nbytes) -> char* {
    char* p = (char*)d_ws + cur;
    cur += (nbytes + 255) & ~(size_t)255;
    return p;
  };
  int* mode = (int*)alloc(4);
  int* cnt = (int*)alloc((size_t)N * 4);
  int* off = (int*)alloc((size_t)N * 4);
  int* cursor = (int*)alloc((size_t)N * 4);
  float* dinv = (float*)alloc((size_t)N * 4);
  int* tot = (int*)alloc(64 * 4);
  int* csr = (int*)alloc((size_t)E * 4);
  __half* W1t = (__half*)alloc(16384 * 2);
  __half* W2t = (__half*)alloc(16384 * 2);
  __half* Wih_h = (__half*)alloc(65536 * 2);
  __half* Wlin_h = (__half*)alloc(8192 * 2);
  __half* Ph = (__half*)alloc((size_t)N * 128 * 2);
  __half* Qh = (__half*)alloc((size_t)N * 128 * 2);
  __half* XP = (__half*)alloc((size_t)N * 512 * 2);
  __half* HLh = (__half*)alloc((size_t)N * 128 * 2);

  hipMemsetAsync(cnt, 0, (size_t)N * 4, stream);
  detect_k<<<1, 64, 0, stream>>>(eidx, mode);
  deg_k<<<1024, 256, 0, stream>>>(eidx, mode, cnt, E);
  const int nb = (N + 1023) / 1024;
  scan1_k<<<nb, 1024, 0, stream>>>(cnt, off, tot, N);
  scan2_k<<<1, 64, 0, stream>>>(tot, nb);
  scan3_k<<<(N + 255) / 256, 256, 0, stream>>>(off, tot, cursor, cnt, dinv, N);
  fill_k<<<1024, 256, 0, stream>>>(eidx, mode, cursor, csr, E);

  // fused weight prep (one launch, 106496 elements)
  wprep_k<<<(106496 + 255) / 256, 256, 0, stream>>>(W1, W2, Wih, Wlin, W1t, W2t,
                                                    Wih_h, Wlin_h);

  const int gx = (N + 63) / 64;
  const int ga = (N + 15) / 16;  // agg: 16 nodes per 256-thread block
  // conv1: Ph = f16((x@W1)*dinv) — reads f32 x directly (AF32)
  mgemm_k<0, true><<<dim3(2, gx), 256, 0, stream>>>(x, W1t, nullptr, Ph, 128,
                                                    dinv, nullptr, nullptr, N);
  agg_k<<<ga, 256, 0, stream>>>(Ph, off, cnt, csr, dinv, b1, Qh, N);
  // conv2
  mgemm_k<0, false><<<dim3(2, gx), 256, 0, stream>>>(Qh, W2t, nullptr, Ph, 128,
                                                     dinv, nullptr, nullptr, N);
  agg_k<<<ga, 256, 0, stream>>>(Ph, off, cnt, csr, dinv, b2, Qh, N);
  // x_proj = Qh @ Wih^T + (bih + bhh) -> f16
  mgemm_k<1, false><<<dim3(8, gx), 256, 0, stream>>>(Qh, Wih_h, nullptr, XP, 512,
                                                     nullptr, bih, bhh, N);
  // chunked LSTM
  const int L = (N + NCHUNK - 1) / NCHUNK;
  lstm_k<<<NCHUNK, 512, 0, stream>>>(XP, Whh, HLh, N, L);
  // final linear: out = HL @ Wlin^T + blin (f32 out)
  mgemm_k<2, false><<<dim3(1, gx), 256, 0, stream>>>(HLh, Wlin_h, out, nullptr,
                                                     64, nullptr, blin, nullptr,
                                                     N);
}